// Round 5
// baseline (822.907 us; speedup 1.0000x reference)
//
#include <hip/hip_runtime.h>
#include <hip/hip_fp16.h>

#define IDIM 512
#define HDIM 512
#define NGATE 2048
#define SEGS 128
#define BATCH 64
#define ZK 0.1f
#define XGROWS 98304  // hard bound: 8192 segs * max dur 12

typedef _Float16 f16;
typedef _Float16 f16x8 __attribute__((ext_vector_type(8)));
typedef float f32x4 __attribute__((ext_vector_type(4)));

__device__ __forceinline__ void gload16(const void* g, void* l) {
  __builtin_amdgcn_global_load_lds((const __attribute__((address_space(1))) void*)g,
                                   (__attribute__((address_space(3))) void*)l, 16, 0, 0);
}
__device__ __forceinline__ float sigmoidf_(float x) { return 1.0f / (1.0f + __expf(-x)); }
__device__ __forceinline__ float tanhf_(float x) { return 2.0f / (1.0f + __expf(-2.0f * x)) - 1.0f; }

// ---- prep: counting-sort segments by dur desc; Mk[0..11], Off[12..23], total Mk[24], mel ----
__global__ void prep_kernel(const int* __restrict__ durs, int4* __restrict__ meta,
                            int* __restrict__ Mk, int* __restrict__ mel) {
  __shared__ int hist[16];
  __shared__ int cur[16];
  int tid = threadIdx.x;  // 64 threads
  if (tid < 16) hist[tid] = 0;
  __syncthreads();
  int b = tid;
  for (int s = 0; s < SEGS; ++s) atomicAdd(&hist[durs[s * BATCH + b] & 15], 1);
  __syncthreads();
  if (tid == 0) {
    int run = 0;
    for (int d = 15; d >= 0; --d) { cur[d] = run; run += hist[d]; }
    int off = 0;
    for (int kk = 0; kk < 12; ++kk) { Mk[kk] = cur[kk]; Mk[12 + kk] = off; off += cur[kk]; }
    Mk[24] = off;  // total seg-steps = sum(durs)
  }
  __syncthreads();
  int run = 0;
  for (int s = 0; s < SEGS; ++s) {
    int d = durs[s * BATCH + b] & 15;
    int pos = atomicAdd(&cur[d], 1);
    meta[pos] = make_int4(run, b, s, d);  // start, b, s, dur
    run += d;
  }
  mel[b] = run;
}

// ---- zero rowmap (poison-proof: unfilled slots -> row 0) ----
__global__ void zrowmap_kernel(int* __restrict__ rowmap) {
  rowmap[blockIdx.x * 256 + threadIdx.x] = 0;
}

// ---- rowmap[Off[k]+m] = x-row index (t*B+b) for sorted segment m at step k ----
__global__ void rowmap_kernel(const int4* __restrict__ meta, const int* __restrict__ Mk,
                              int* __restrict__ rowmap) {
  int k = blockIdx.y;
  int m = blockIdx.x * 256 + threadIdx.x;
  if (m < Mk[k]) {
    int4 mt = meta[m];
    rowmap[Mk[12 + k] + m] = (mt.x + k) * BATCH + mt.y;
  }
}

// ---- W prep: permuted Wih / Whh (fp16), bias (bih+bhh) ----
__global__ void wprep_kernel(const float* __restrict__ Wih, const float* __restrict__ Whh,
                             const float* __restrict__ bih, const float* __restrict__ bhh,
                             f16* __restrict__ Wihp, f16* __restrict__ Whhp,
                             float* __restrict__ biasp) {
  int n = blockIdx.x;
  int G = n >> 6, q = (n >> 4) & 3, r = n & 15;
  int orig = q * 512 + G * 16 + r;
  for (int kk = threadIdx.x; kk < 512; kk += blockDim.x) {
    Wihp[(size_t)n * 512 + kk] = (f16)Wih[(size_t)orig * 512 + kk];
    Whhp[(size_t)n * 512 + kk] = (f16)Whh[(size_t)orig * 512 + kk];
  }
  if (threadIdx.x == 0) biasp[n] = bih[orig] + bhh[orig];
}

// ---- x: fp32 -> fp16 ----
__global__ void xconv_kernel(const float* __restrict__ x, f16* __restrict__ xh, long n8) {
  long i = (long)blockIdx.x * blockDim.x + threadIdx.x;
  long stride = (long)gridDim.x * blockDim.x;
  for (; i < n8; i += stride) {
    const float4* p = (const float4*)(x + i * 8);
    float4 a = p[0], bv = p[1];
    f16x8 o;
    o[0] = (f16)a.x;  o[1] = (f16)a.y;  o[2] = (f16)a.z;  o[3] = (f16)a.w;
    o[4] = (f16)bv.x; o[5] = (f16)bv.y; o[6] = (f16)bv.z; o[7] = (f16)bv.w;
    *(f16x8*)(xh + i * 8) = o;
  }
}

// ---- zero invalid output rows + h + c (grid-stride) ----
__global__ void zero_kernel(float* __restrict__ out, const int* __restrict__ mel,
                            int T, int total) {
  int tb = T * BATCH;
  for (int bid = blockIdx.x; bid < total; bid += gridDim.x) {
    if (bid < tb) {
      int t = bid / BATCH, b = bid - t * BATCH;
      if (t < mel[b]) continue;
      float4* p = (float4*)(out + (size_t)bid * HDIM);
      p[threadIdx.x] = make_float4(0.f, 0.f, 0.f, 0.f);
    } else {
      int e = bid - tb;
      float4* p = (float4*)(out + (size_t)tb * HDIM + (size_t)e * HDIM);
      p[threadIdx.x] = make_float4(0.f, 0.f, 0.f, 0.f);
    }
  }
}

// ============ PHASE A: xg = x @ Wih^T + bias, M=total N=2048 K=512, fp16 out ============
__global__ __launch_bounds__(512, 1)
void xg_gemm_kernel(const f16* __restrict__ xh, const f16* __restrict__ Wihp,
                    const float* __restrict__ biasp, const int* __restrict__ rowmap,
                    const int* __restrict__ Mk, f16* __restrict__ xg) {
  // grid (8, 384) = 3072 blocks; bijective XCD swizzle
  const int orig = blockIdx.y * 8 + blockIdx.x;
  const int swz = (orig & 7) * 384 + (orig >> 3);
  const int by = swz >> 3, bx = swz & 7;
  const int r0 = by * 256;
  if (r0 >= Mk[24]) return;  // beyond actual total seg-steps
  const int n0 = bx * 256;

  __shared__ __align__(16) f16 SM[65536];  // 128 KB: As[2][256][64] | Bs[2][256][64]
  f16 (*As)[256][64] = (f16(*)[256][64])SM;
  f16 (*Bs)[256][64] = (f16(*)[256][64])(SM + 32768);

  const int tid = threadIdx.x;
  const int lane = tid & 63;
  const int w = tid >> 6;
  const int wr = w >> 2;
  const int wc = w & 3;
  const int lr = lane & 15;
  const int lk = lane >> 4;

  const int swzc = (((lane & 7) ^ ((lane >> 3) & 7)) << 3);
  const f16* asrc[4];
  const f16* wsrc[4];
#pragma unroll
  for (int o = 0; o < 4; ++o) {
    int trow = o * 64 + w * 8 + (lane >> 3);
    asrc[o] = xh + (size_t)rowmap[r0 + trow] * IDIM + swzc;
    wsrc[o] = Wihp + (size_t)(n0 + trow) * 512 + swzc;
  }

  auto stageA = [&](int o, int kb, int slot) {
    gload16(asrc[o] + kb * 64, &As[slot][o * 64 + w * 8][0]);
  };
  auto stageB = [&](int o, int kb, int slot) {
    gload16(wsrc[o] + kb * 64, &Bs[slot][o * 64 + w * 8][0]);
  };
  auto lda = [&](int slot, int h, int f, int ks) -> f16x8 {
    int row = wr * 128 + h * 64 + f * 16 + lr;
    int ch = (((ks * 4 + lk) ^ (lr & 7)) << 3);
    return *(const f16x8*)&As[slot][row][ch];
  };
  auto ldb = [&](int slot, int q, int ks) -> f16x8 {
    int row = wc * 64 + q * 16 + lr;
    int ch = (((ks * 4 + lk) ^ (lr & 7)) << 3);
    return *(const f16x8*)&Bs[slot][row][ch];
  };

  f32x4 acc[8][4];
#pragma unroll
  for (int a = 0; a < 8; ++a)
#pragma unroll
    for (int bb = 0; bb < 4; ++bb) acc[a][bb] = (f32x4){0.f, 0.f, 0.f, 0.f};

  const int KB = 8;
#pragma unroll
  for (int o = 0; o < 4; ++o) stageA(o, 0, 0);
#pragma unroll
  for (int o = 0; o < 4; ++o) stageB(o, 0, 0);
#pragma unroll
  for (int o = 0; o < 4; ++o) stageA(o, 1, 1);
#pragma unroll
  for (int o = 0; o < 4; ++o) stageB(o, 1, 1);
  asm volatile("s_waitcnt vmcnt(8)" ::: "memory");
  __builtin_amdgcn_s_barrier();

  f16x8 aF[4][2], bF[4][2];
  for (int kt = 0; kt < KB; ++kt) {
    const int s = kt & 1;
    const bool st1 = (kt + 1 < KB);
    const bool st2 = (kt + 2 < KB);

#pragma unroll
    for (int f = 0; f < 4; ++f)
#pragma unroll
      for (int ks = 0; ks < 2; ++ks) aF[f][ks] = lda(s, 0, f, ks);
#pragma unroll
    for (int q = 0; q < 4; ++q)
#pragma unroll
      for (int ks = 0; ks < 2; ++ks) bF[q][ks] = ldb(s, q, ks);
    __builtin_amdgcn_s_barrier();
    __builtin_amdgcn_s_setprio(1);
#pragma unroll
    for (int f = 0; f < 4; ++f)
#pragma unroll
      for (int fn = 0; fn < 2; ++fn)
#pragma unroll
        for (int ks = 0; ks < 2; ++ks)
          acc[f][fn] = __builtin_amdgcn_mfma_f32_16x16x32_f16(aF[f][ks], bF[fn][ks], acc[f][fn], 0, 0, 0);
    __builtin_amdgcn_s_setprio(0);
    __builtin_amdgcn_s_barrier();

    if (st2) {
#pragma unroll
      for (int o = 0; o < 4; ++o) stageB(o, kt + 2, s);
    }
    __builtin_amdgcn_s_barrier();
    __builtin_amdgcn_s_setprio(1);
#pragma unroll
    for (int f = 0; f < 4; ++f)
#pragma unroll
      for (int fn = 2; fn < 4; ++fn)
#pragma unroll
        for (int ks = 0; ks < 2; ++ks)
          acc[f][fn] = __builtin_amdgcn_mfma_f32_16x16x32_f16(aF[f][ks], bF[fn][ks], acc[f][fn], 0, 0, 0);
    __builtin_amdgcn_s_setprio(0);
    __builtin_amdgcn_s_barrier();

#pragma unroll
    for (int f = 0; f < 4; ++f)
#pragma unroll
      for (int ks = 0; ks < 2; ++ks) aF[f][ks] = lda(s, 1, f, ks);
    if (st2) { stageA(0, kt + 2, s); stageA(2, kt + 2, s); }
    __builtin_amdgcn_s_barrier();
    __builtin_amdgcn_s_setprio(1);
#pragma unroll
    for (int f = 0; f < 4; ++f)
#pragma unroll
      for (int fn = 0; fn < 2; ++fn)
#pragma unroll
        for (int ks = 0; ks < 2; ++ks)
          acc[4 + f][fn] = __builtin_amdgcn_mfma_f32_16x16x32_f16(aF[f][ks], bF[fn][ks], acc[4 + f][fn], 0, 0, 0);
    __builtin_amdgcn_s_setprio(0);
    __builtin_amdgcn_s_barrier();

    if (st2) { stageA(1, kt + 2, s); stageA(3, kt + 2, s); }
    __builtin_amdgcn_s_setprio(1);
#pragma unroll
    for (int f = 0; f < 4; ++f)
#pragma unroll
      for (int fn = 2; fn < 4; ++fn)
#pragma unroll
        for (int ks = 0; ks < 2; ++ks)
          acc[4 + f][fn] = __builtin_amdgcn_mfma_f32_16x16x32_f16(aF[f][ks], bF[fn][ks], acc[4 + f][fn], 0, 0, 0);
    __builtin_amdgcn_s_setprio(0);
    if (st2) {
      asm volatile("s_waitcnt vmcnt(8)" ::: "memory");
    } else if (st1) {
      asm volatile("s_waitcnt vmcnt(0)" ::: "memory");
    }
    __builtin_amdgcn_s_barrier();
  }

  // ---- epilogue: +bias, fp16, LDS repack, coalesced store ----
  float bq[4];
#pragma unroll
  for (int q = 0; q < 4; ++q) bq[q] = biasp[n0 + wc * 64 + q * 16 + lr];
  __syncthreads();
  f16* SM2 = SM;  // [256][256]
#pragma unroll
  for (int fm = 0; fm < 8; ++fm)
#pragma unroll
    for (int reg = 0; reg < 4; ++reg) {
      int lm = wr * 128 + fm * 16 + ((lane >> 4) << 2) + reg;
#pragma unroll
      for (int q = 0; q < 4; ++q)
        SM2[lm * 256 + wc * 64 + q * 16 + lr] = (f16)(acc[fm][q][reg] + bq[q]);
    }
  __syncthreads();
#pragma unroll
  for (int i = 0; i < 16; ++i) {
    int idx = i * 512 + tid;
    int lm = idx >> 5, c = idx & 31;
    *(f16x8*)(xg + ((size_t)(r0 + lm) * NGATE + n0 + c * 8)) =
        *(const f16x8*)&SM2[lm * 256 + c * 8];
  }
}

// ---- step 0: gates = xg row (h=c=0), epilogue only ----
__global__ void step0_kernel(const f16* __restrict__ xg, const int4* __restrict__ meta,
                             f16* __restrict__ hnext, float* __restrict__ cst,
                             float* __restrict__ out) {
  __shared__ f16 xr[NGATE];
  int m = blockIdx.x;
  int tid = threadIdx.x;  // 256
  *(f16x8*)&xr[tid * 8] = *(const f16x8*)&xg[(size_t)m * NGATE + tid * 8];
  __syncthreads();
  int4 mt = meta[m];
#pragma unroll
  for (int u = 0; u < 2; ++u) {
    int jj = tid * 2 + u;
    int base = (jj >> 4) * 64 + (jj & 15);
    float iv = sigmoidf_((float)xr[base]);
    float gv = tanhf_((float)xr[base + 32]);
    float ov = sigmoidf_((float)xr[base + 48]);
    float cn = iv * gv;
    float hn = ov * tanhf_(cn);
    float hz = (1.f - ZK) * hn, cz = (1.f - ZK) * cn;
    out[((size_t)mt.x * BATCH + mt.y) * HDIM + jj] = hz;
    hnext[(size_t)m * HDIM + jj] = (f16)hz;
    cst[(size_t)m * HDIM + jj] = cz;
  }
}

// ============ HEAD steps k>=1: 256x256xK512, depth-2 counted vmcnt ============
__global__ __launch_bounds__(512, 1)
void step256_kernel(const f16* __restrict__ xg, const f16* __restrict__ Whhp,
                    const f16* __restrict__ hprev, f16* __restrict__ hnext,
                    float* __restrict__ cst,
                    const int4* __restrict__ meta, const int* __restrict__ Mk,
                    float* __restrict__ out, int T, int k) {
  const int mk = Mk[k];
  const int offk = Mk[12 + k];
  const int nbx = gridDim.x;
  const int nwg = nbx * gridDim.y;
  const int orig = blockIdx.y * nbx + blockIdx.x;
  const int cpx = nwg >> 3;
  const int swz = (orig & 7) * cpx + (orig >> 3);
  const int by = swz / nbx, bx = swz - by * nbx;
  const int m0 = by * 256;
  if (m0 >= mk) return;
  const int n0 = bx * 256;

  __shared__ __align__(16) f16 As[2][256][64];
  __shared__ __align__(16) f16 Bs[2][256][64];
  __shared__ int4 metaS[256];

  const int tid = threadIdx.x;
  const int lane = tid & 63;
  const int w = tid >> 6;
  const int wr = w >> 2;
  const int wc = w & 3;
  const int lr = lane & 15;
  const int lk = lane >> 4;

  if (tid < 256) metaS[tid] = meta[m0 + tid];

  const int swzc = (((lane & 7) ^ ((lane >> 3) & 7)) << 3);
  const f16* asrc[4];
  const f16* wsrc[4];
#pragma unroll
  for (int o = 0; o < 4; ++o) {
    int trow = o * 64 + w * 8 + (lane >> 3);
    int r = m0 + trow;
    int ra = (r < mk) ? r : 0;
    asrc[o] = hprev + (size_t)ra * HDIM + swzc;
    wsrc[o] = Whhp + (size_t)(n0 + trow) * 512 + swzc;
  }

  auto stageA = [&](int o, int kb, int slot) {
    gload16(asrc[o] + kb * 64, &As[slot][o * 64 + w * 8][0]);
  };
  auto stageB = [&](int o, int kb, int slot) {
    gload16(wsrc[o] + kb * 64, &Bs[slot][o * 64 + w * 8][0]);
  };
  auto lda = [&](int slot, int h, int f, int ks) -> f16x8 {
    int row = wr * 128 + h * 64 + f * 16 + lr;
    int ch = (((ks * 4 + lk) ^ (lr & 7)) << 3);
    return *(const f16x8*)&As[slot][row][ch];
  };
  auto ldb = [&](int slot, int q, int ks) -> f16x8 {
    int row = wc * 64 + q * 16 + lr;
    int ch = (((ks * 4 + lk) ^ (lr & 7)) << 3);
    return *(const f16x8*)&Bs[slot][row][ch];
  };

  f32x4 acc[8][4];
#pragma unroll
  for (int a = 0; a < 8; ++a)
#pragma unroll
    for (int bb = 0; bb < 4; ++bb) acc[a][bb] = (f32x4){0.f, 0.f, 0.f, 0.f};

  const int KB = 8;
#pragma unroll
  for (int o = 0; o < 4; ++o) stageA(o, 0, 0);
#pragma unroll
  for (int o = 0; o < 4; ++o) stageB(o, 0, 0);
#pragma unroll
  for (int o = 0; o < 4; ++o) stageA(o, 1, 1);
#pragma unroll
  for (int o = 0; o < 4; ++o) stageB(o, 1, 1);
  asm volatile("s_waitcnt vmcnt(8)" ::: "memory");
  __builtin_amdgcn_s_barrier();

  f16x8 aF[4][2], bF[4][2];
  for (int kt = 0; kt < KB; ++kt) {
    const int s = kt & 1;
    const bool st1 = (kt + 1 < KB);
    const bool st2 = (kt + 2 < KB);

#pragma unroll
    for (int f = 0; f < 4; ++f)
#pragma unroll
      for (int ks = 0; ks < 2; ++ks) aF[f][ks] = lda(s, 0, f, ks);
#pragma unroll
    for (int q = 0; q < 4; ++q)
#pragma unroll
      for (int ks = 0; ks < 2; ++ks) bF[q][ks] = ldb(s, q, ks);
    __builtin_amdgcn_s_barrier();
    __builtin_amdgcn_s_setprio(1);
#pragma unroll
    for (int f = 0; f < 4; ++f)
#pragma unroll
      for (int fn = 0; fn < 2; ++fn)
#pragma unroll
        for (int ks = 0; ks < 2; ++ks)
          acc[f][fn] = __builtin_amdgcn_mfma_f32_16x16x32_f16(aF[f][ks], bF[fn][ks], acc[f][fn], 0, 0, 0);
    __builtin_amdgcn_s_setprio(0);
    __builtin_amdgcn_s_barrier();

    if (st2) {
#pragma unroll
      for (int o = 0; o < 4; ++o) stageB(o, kt + 2, s);
    }
    __builtin_amdgcn_s_barrier();
    __builtin_amdgcn_s_setprio(1);
#pragma unroll
    for (int f = 0; f < 4; ++f)
#pragma unroll
      for (int fn = 2; fn < 4; ++fn)
#pragma unroll
        for (int ks = 0; ks < 2; ++ks)
          acc[f][fn] = __builtin_amdgcn_mfma_f32_16x16x32_f16(aF[f][ks], bF[fn][ks], acc[f][fn], 0, 0, 0);
    __builtin_amdgcn_s_setprio(0);
    __builtin_amdgcn_s_barrier();

#pragma unroll
    for (int f = 0; f < 4; ++f)
#pragma unroll
      for (int ks = 0; ks < 2; ++ks) aF[f][ks] = lda(s, 1, f, ks);
    if (st2) { stageA(0, kt + 2, s); stageA(2, kt + 2, s); }
    __builtin_amdgcn_s_barrier();
    __builtin_amdgcn_s_setprio(1);
#pragma unroll
    for (int f = 0; f < 4; ++f)
#pragma unroll
      for (int fn = 0; fn < 2; ++fn)
#pragma unroll
        for (int ks = 0; ks < 2; ++ks)
          acc[4 + f][fn] = __builtin_amdgcn_mfma_f32_16x16x32_f16(aF[f][ks], bF[fn][ks], acc[4 + f][fn], 0, 0, 0);
    __builtin_amdgcn_s_setprio(0);
    __builtin_amdgcn_s_barrier();

    if (st2) { stageA(1, kt + 2, s); stageA(3, kt + 2, s); }
    __builtin_amdgcn_s_setprio(1);
#pragma unroll
    for (int f = 0; f < 4; ++f)
#pragma unroll
      for (int fn = 2; fn < 4; ++fn)
#pragma unroll
        for (int ks = 0; ks < 2; ++ks)
          acc[4 + f][fn] = __builtin_amdgcn_mfma_f32_16x16x32_f16(aF[f][ks], bF[fn][ks], acc[4 + f][fn], 0, 0, 0);
    __builtin_amdgcn_s_setprio(0);
    if (st2) {
      asm volatile("s_waitcnt vmcnt(8)" ::: "memory");
    } else if (st1) {
      asm volatile("s_waitcnt vmcnt(0)" ::: "memory");
    }
    __builtin_amdgcn_s_barrier();
  }

  // ---- fused LSTM epilogue (gates = acc + xg) ----
  const int nb = n0 + wc * 64 + lr;
  const size_t segoff = (size_t)T * BATCH * HDIM + (size_t)2 * BATCH * HDIM;
  const int j = ((n0 + wc * 64) >> 6) * 16 + lr;

#pragma unroll
  for (int fm = 0; fm < 8; ++fm) {
#pragma unroll
    for (int reg = 0; reg < 4; ++reg) {
      int m = m0 + wr * 128 + fm * 16 + ((lane >> 4) << 2) + reg;
      if (m >= mk) continue;
      int4 mt = metaS[m - m0];
      const f16* xgp = xg + (size_t)(offk + m) * NGATE;
      float gi = acc[fm][0][reg] + (float)xgp[nb];
      float gf = acc[fm][1][reg] + (float)xgp[nb + 16];
      float gg = acc[fm][2][reg] + (float)xgp[nb + 32];
      float go = acc[fm][3][reg] + (float)xgp[nb + 48];
      float iv = sigmoidf_(gi), fv = sigmoidf_(gf);
      float gv = tanhf_(gg), ov = sigmoidf_(go);
      float cp = cst[(size_t)m * HDIM + j];
      float hp = (float)hprev[(size_t)m * HDIM + j];
      float cn = fv * cp + iv * gv;
      float hn = ov * tanhf_(cn);
      float hz = ZK * hp + (1.f - ZK) * hn;
      float cz = ZK * cp + (1.f - ZK) * cn;
      out[((size_t)(mt.x + k) * BATCH + mt.y) * HDIM + j] = hz;
      if (k == mt.w - 1) {
        out[segoff + ((size_t)mt.y * SEGS + mt.z) * HDIM + j] = hz;
      } else {
        hnext[(size_t)m * HDIM + j] = (f16)hz;
        cst[(size_t)m * HDIM + j] = cz;
      }
    }
  }
}

// ============ TAIL steps: 128x128xK512, 4 waves ============
__global__ void step_kernel(const f16* __restrict__ xg, const f16* __restrict__ Whhp,
                            const f16* __restrict__ hprev, f16* __restrict__ hnext,
                            float* __restrict__ cst,
                            const int4* __restrict__ meta, const int* __restrict__ Mk,
                            float* __restrict__ out, int T, int k) {
  const int mk = Mk[k];
  const int offk = Mk[12 + k];
  const int m0 = blockIdx.y * 128;
  if (m0 >= mk) return;
  const int n0 = blockIdx.x * 128;

  __shared__ __align__(16) f16 At[128][64];
  __shared__ __align__(16) f16 Bt[128][64];
  __shared__ int4 metaS[128];

  const int tid = threadIdx.x;
  const int lane = tid & 63;
  const int w = tid >> 6;
  const int wr = w >> 1, wc = w & 1;

  if (tid < 128) metaS[tid] = meta[m0 + tid];

  const f16* hsrc[4];
  const f16* wsrc[4];
#pragma unroll
  for (int i = 0; i < 4; ++i) {
    int r = m0 + w * 32 + i * 8 + (lane >> 3);
    int ra = (r < mk) ? r : 0;
    hsrc[i] = hprev + (size_t)ra * HDIM;
    wsrc[i] = Whhp + (size_t)(n0 + w * 32 + i * 8 + (lane >> 3)) * 512;
  }
  const int koff = (lane & 7) * 8;

  f32x4 acc[4][4];
#pragma unroll
  for (int a = 0; a < 4; ++a)
#pragma unroll
    for (int bb = 0; bb < 4; ++bb) acc[a][bb] = (f32x4){0.f, 0.f, 0.f, 0.f};

  for (int kb = 0; kb < 8; ++kb) {
    __syncthreads();
#pragma unroll
    for (int i = 0; i < 4; ++i) gload16(hsrc[i] + kb * 64 + koff, &At[w * 32 + i * 8][0]);
#pragma unroll
    for (int i = 0; i < 4; ++i) gload16(wsrc[i] + kb * 64 + koff, &Bt[w * 32 + i * 8][0]);
    __syncthreads();

    const int lr = lane & 15;
    const int lk = (lane >> 4) * 8;
#pragma unroll
    for (int ks = 0; ks < 2; ++ks) {
      f16x8 af[4], bfr[4];
#pragma unroll
      for (int f = 0; f < 4; ++f) af[f] = *(const f16x8*)&At[wr * 64 + f * 16 + lr][ks * 32 + lk];
#pragma unroll
      for (int f = 0; f < 4; ++f) bfr[f] = *(const f16x8*)&Bt[wc * 64 + f * 16 + lr][ks * 32 + lk];
#pragma unroll
      for (int fm = 0; fm < 4; ++fm)
#pragma unroll
        for (int fn = 0; fn < 4; ++fn)
          acc[fm][fn] = __builtin_amdgcn_mfma_f32_16x16x32_f16(af[fm], bfr[fn], acc[fm][fn], 0, 0, 0);
    }
  }

  const int r15 = lane & 15;
  const int nb = n0 + wc * 64 + r15;
  const int j = ((n0 + wc * 64) >> 6) * 16 + r15;
  const size_t segoff = (size_t)T * BATCH * HDIM + (size_t)2 * BATCH * HDIM;

#pragma unroll
  for (int fm = 0; fm < 4; ++fm) {
#pragma unroll
    for (int reg = 0; reg < 4; ++reg) {
      int m = m0 + wr * 64 + fm * 16 + ((lane >> 4) << 2) + reg;
      if (m >= mk) continue;
      int4 mt = metaS[m - m0];
      const f16* xgp = xg + (size_t)(offk + m) * NGATE;
      float gi = acc[fm][0][reg] + (float)xgp[nb];
      float gf = acc[fm][1][reg] + (float)xgp[nb + 16];
      float gg = acc[fm][2][reg] + (float)xgp[nb + 32];
      float go = acc[fm][3][reg] + (float)xgp[nb + 48];
      float iv = sigmoidf_(gi), fv = sigmoidf_(gf);
      float gv = tanhf_(gg), ov = sigmoidf_(go);
      float cp = cst[(size_t)m * HDIM + j];
      float hp = (float)hprev[(size_t)m * HDIM + j];
      float cn = fv * cp + iv * gv;
      float hn = ov * tanhf_(cn);
      float hz = ZK * hp + (1.f - ZK) * hn;
      float cz = ZK * cp + (1.f - ZK) * cn;
      out[((size_t)(mt.x + k) * BATCH + mt.y) * HDIM + j] = hz;
      if (k == mt.w - 1) {
        out[segoff + ((size_t)mt.y * SEGS + mt.z) * HDIM + j] = hz;
      } else {
        hnext[(size_t)m * HDIM + j] = (f16)hz;
        cst[(size_t)m * HDIM + j] = cz;
      }
    }
  }
}

extern "C" void kernel_launch(void* const* d_in, const int* in_sizes, int n_in,
                              void* d_out, int out_size, void* d_ws, size_t ws_size,
                              hipStream_t stream) {
  const float* x = (const float*)d_in[0];
  const int* durs = (const int*)d_in[1];
  const float* Wih = (const float*)d_in[2];
  const float* Whh = (const float*)d_in[3];
  const float* bih = (const float*)d_in[4];
  const float* bhh = (const float*)d_in[5];
  float* out = (float*)d_out;
  const int T = in_sizes[0] / (BATCH * IDIM);

  char* ws = (char*)d_ws;
  size_t off = 0;
  auto alloc = [&](size_t bytes) {
    void* p = ws + off;
    off = (off + bytes + 255) & ~(size_t)255;
    return p;
  };
  f16* xh      = (f16*)alloc((size_t)T * BATCH * IDIM * 2);
  f16* xg      = (f16*)alloc((size_t)XGROWS * NGATE * 2);  // 403 MB, hard upper bound
  f16* Wihp    = (f16*)alloc((size_t)NGATE * 512 * 2);
  f16* Whhp    = (f16*)alloc((size_t)NGATE * 512 * 2);
  float* biasp = (float*)alloc((size_t)NGATE * 4);
  f16* hst0    = (f16*)alloc((size_t)SEGS * BATCH * HDIM * 2);
  f16* hst1    = (f16*)alloc((size_t)SEGS * BATCH * HDIM * 2);
  float* cst   = (float*)alloc((size_t)SEGS * BATCH * HDIM * 4);
  int4* meta   = (int4*)alloc((size_t)SEGS * BATCH * 16);
  int* Mk      = (int*)alloc(256);
  int* mel     = (int*)alloc(64);
  int* rowmap  = (int*)alloc((size_t)XGROWS * 4);

  prep_kernel<<<1, 64, 0, stream>>>(durs, meta, Mk, mel);
  wprep_kernel<<<NGATE, 256, 0, stream>>>(Wih, Whh, bih, bhh, Wihp, Whhp, biasp);
  long n8 = (long)T * BATCH * IDIM / 8;
  xconv_kernel<<<2048, 256, 0, stream>>>(x, xh, n8);
  zero_kernel<<<2048, 128, 0, stream>>>(out, mel, T, T * BATCH + 128);
  zrowmap_kernel<<<XGROWS / 256, 256, 0, stream>>>(rowmap);
  rowmap_kernel<<<dim3(32, 12), 256, 0, stream>>>(meta, Mk, rowmap);

  // Phase A: all-timestep input projection (one big GEMM, early-exit past total)
  xg_gemm_kernel<<<dim3(8, 384), 512, 0, stream>>>(xh, Wihp, biasp, rowmap, Mk, xg);

  // Step 0: epilogue only (h=c=0), writes hst1/cst
  step0_kernel<<<SEGS * BATCH, 256, 0, stream>>>(xg, meta, hst1, cst, out);

  // Steps 1..7: 256^2 head
  dim3 hgrid(8, 32);
  for (int k = 1; k < 8; ++k) {
    f16* hp = (k & 1) ? hst1 : hst0;
    f16* hn = (k & 1) ? hst0 : hst1;
    step256_kernel<<<hgrid, 512, 0, stream>>>(xg, Whhp, hp, hn, cst, meta, Mk, out, T, k);
  }
  // Steps 8..11: 128^2 tail
  dim3 sgrid(16, 64);
  for (int k = 8; k < 12; ++k) {
    f16* hp = (k & 1) ? hst1 : hst0;
    f16* hn = (k & 1) ? hst0 : hst1;
    step_kernel<<<sgrid, 256, 0, stream>>>(xg, Whhp, hp, hn, cst, meta, Mk, out, T, k);
  }
}

// Round 6
// 725.668 us; speedup vs baseline: 1.1340x; 1.1340x over previous
//
#include <hip/hip_runtime.h>
#include <hip/hip_fp16.h>

#define IDIM 512
#define HDIM 512
#define NGATE 2048
#define SEGS 128
#define BATCH 64
#define ZK 0.1f

typedef _Float16 f16;
typedef _Float16 f16x8 __attribute__((ext_vector_type(8)));
typedef float f32x4 __attribute__((ext_vector_type(4)));

__device__ __forceinline__ void gload16(const void* g, void* l) {
  __builtin_amdgcn_global_load_lds((const __attribute__((address_space(1))) void*)g,
                                   (__attribute__((address_space(3))) void*)l, 16, 0, 0);
}
__device__ __forceinline__ float sigmoidf_(float x) { return 1.0f / (1.0f + __expf(-x)); }
__device__ __forceinline__ float tanhf_(float x) { return 2.0f / (1.0f + __expf(-2.0f * x)) - 1.0f; }

// ---------------- prep: starts, counting-sort by dur desc, Mk, mel_len ----------------
__global__ void prep_kernel(const int* __restrict__ durs, int4* __restrict__ meta,
                            int* __restrict__ Mk, int* __restrict__ mel) {
  __shared__ int hist[16];
  __shared__ int cur[16];
  int tid = threadIdx.x;  // 64 threads, one per batch element
  if (tid < 16) hist[tid] = 0;
  __syncthreads();
  int b = tid;
  for (int s = 0; s < SEGS; ++s) atomicAdd(&hist[durs[s * BATCH + b] & 15], 1);
  __syncthreads();
  if (tid == 0) {
    int run = 0;
    for (int d = 15; d >= 0; --d) { cur[d] = run; run += hist[d]; }
    for (int kk = 0; kk < 12; ++kk) Mk[kk] = cur[kk];
  }
  __syncthreads();
  int run = 0;
  for (int s = 0; s < SEGS; ++s) {
    int d = durs[s * BATCH + b] & 15;
    int pos = atomicAdd(&cur[d], 1);
    meta[pos] = make_int4(run, b, s, d);  // start, b, s, dur
    run += d;
  }
  mel[b] = run;
}

// ---------------- W prep: permuted combined weight (fp16) + bias ----------------
__global__ void wprep_kernel(const float* __restrict__ Wih, const float* __restrict__ Whh,
                             const float* __restrict__ bih, const float* __restrict__ bhh,
                             f16* __restrict__ Wc, float* __restrict__ biasp) {
  int n = blockIdx.x;
  int G = n >> 6, q = (n >> 4) & 3, r = n & 15;
  int j = G * 16 + r;
  int orig = q * 512 + j;
  for (int kk = threadIdx.x; kk < 1024; kk += blockDim.x) {
    float v = (kk < 512) ? Wih[(size_t)orig * 512 + kk] : Whh[(size_t)orig * 512 + kk - 512];
    Wc[(size_t)n * 1024 + kk] = (f16)v;
  }
  if (threadIdx.x == 0) biasp[n] = bih[orig] + bhh[orig];
}

// ---------------- x: fp32 -> fp16 ----------------
__global__ void xconv_kernel(const float* __restrict__ x, f16* __restrict__ xh, long n8) {
  long i = (long)blockIdx.x * blockDim.x + threadIdx.x;
  long stride = (long)gridDim.x * blockDim.x;
  for (; i < n8; i += stride) {
    const float4* p = (const float4*)(x + i * 8);
    float4 a = p[0], bv = p[1];
    f16x8 o;
    o[0] = (f16)a.x;  o[1] = (f16)a.y;  o[2] = (f16)a.z;  o[3] = (f16)a.w;
    o[4] = (f16)bv.x; o[5] = (f16)bv.y; o[6] = (f16)bv.z; o[7] = (f16)bv.w;
    *(f16x8*)(xh + i * 8) = o;
  }
}

// ---------------- zero invalid output rows + h + c (grid-stride) ----------------
__global__ void zero_kernel(float* __restrict__ out, const int* __restrict__ mel,
                            int T, int total) {
  int tb = T * BATCH;
  for (int bid = blockIdx.x; bid < total; bid += gridDim.x) {
    if (bid < tb) {
      int t = bid / BATCH, b = bid - t * BATCH;
      if (t < mel[b]) continue;
      float4* p = (float4*)(out + (size_t)bid * HDIM);
      p[threadIdx.x] = make_float4(0.f, 0.f, 0.f, 0.f);
    } else {
      int e = bid - tb;
      float4* p = (float4*)(out + (size_t)tb * HDIM + (size_t)e * HDIM);
      p[threadIdx.x] = make_float4(0.f, 0.f, 0.f, 0.f);
    }
  }
}

// ============ HEAD: 256x256xBK64 fused (K=1024), 8 waves, depth-2 counted vmcnt ============
// XCD swizzle: ROW-affinity, interleaved (by%8 = xcd) — A-slice (2MB) L2-resident per XCD.
template <bool FIRST>
__global__ __launch_bounds__(512, 1)
void step256_kernel(const f16* __restrict__ xh, const f16* __restrict__ Wc,
                    const float* __restrict__ biasp,
                    const f16* __restrict__ hprev, f16* __restrict__ hnext,
                    float* __restrict__ cst,
                    const int4* __restrict__ meta, const int* __restrict__ Mk,
                    float* __restrict__ out, int T, int k) {
  const int mk = Mk[k];
  // grid (8,32): id 0..255; xcd = id&7 (round-robin dispatch); XCD owns 4 row-blocks
  const int id = blockIdx.y * 8 + blockIdx.x;
  const int xcd = id & 7, slot = id >> 3;       // slot 0..31
  const int by = (slot & 3) * 8 + xcd;          // row-block 0..31, by%8 == xcd
  const int bx = slot >> 2;                     // col-block 0..7
  const int m0 = by * 256;
  if (m0 >= mk) return;
  const int n0 = bx * 256;

  __shared__ __align__(16) f16 As[2][256][64];
  __shared__ __align__(16) f16 Bs[2][256][64];
  __shared__ int4 metaS[256];

  const int tid = threadIdx.x;
  const int lane = tid & 63;
  const int w = tid >> 6;          // 0..7
  const int wr = w >> 2;           // 0..1 : rows wr*128..+128
  const int wc = w & 3;            // 0..3 : cols wc*64..+64
  const int lr = lane & 15;
  const int lk = lane >> 4;        // 0..3

  if (tid < 256) metaS[tid] = meta[m0 + tid];

  // --- staging setup: per-lane gathered sources, pre-swizzled column chunk ---
  const int swzc = (((lane & 7) ^ ((lane >> 3) & 7)) << 3);  // f16 elems within 64-col slice
  size_t xoff[4];
  int ra4[4];
#pragma unroll
  for (int o = 0; o < 4; ++o) {
    int trow = o * 64 + w * 8 + (lane >> 3);
    int r = m0 + trow;
    int ra = (r < mk) ? r : 0;  // dead rows stage row 0 (masked in epilogue)
    int4 mt = meta[ra];
    xoff[o] = ((size_t)(mt.x + k) * BATCH + mt.y) * IDIM + swzc;
    ra4[o] = ra;
  }

  auto stageA = [&](int o, int kb, int slot2) {
    const f16* src;
    if (FIRST || kb < 8) src = xh + xoff[o] + kb * 64;
    else src = hprev + (size_t)ra4[o] * HDIM + (kb - 8) * 64 + swzc;
    gload16(src, &As[slot2][o * 64 + w * 8][0]);
  };
  auto stageB = [&](int o, int kb, int slot2) {
    int trow = o * 64 + w * 8 + (lane >> 3);
    gload16(Wc + (size_t)(n0 + trow) * 1024 + (size_t)kb * 64 + swzc,
            &Bs[slot2][o * 64 + w * 8][0]);
  };

  // --- swizzled fragment reads (conflict-free b128) ---
  auto lda = [&](int slot2, int h, int f, int ks) -> f16x8 {
    int row = wr * 128 + h * 64 + f * 16 + lr;
    int ch = (((ks * 4 + lk) ^ (lr & 7)) << 3);
    return *(const f16x8*)&As[slot2][row][ch];
  };
  auto ldb = [&](int slot2, int q, int ks) -> f16x8 {
    int row = wc * 64 + q * 16 + lr;
    int ch = (((ks * 4 + lk) ^ (lr & 7)) << 3);
    return *(const f16x8*)&Bs[slot2][row][ch];
  };

  f32x4 acc[8][4];
#pragma unroll
  for (int a = 0; a < 8; ++a)
#pragma unroll
    for (int bb = 0; bb < 4; ++bb) acc[a][bb] = (f32x4){0.f, 0.f, 0.f, 0.f};

  const int KB = FIRST ? 8 : 16;

  // prologue: prime tiles 0 (slot 0) and 1 (slot 1); wait tile0 only (counted)
#pragma unroll
  for (int o = 0; o < 4; ++o) stageA(o, 0, 0);
#pragma unroll
  for (int o = 0; o < 4; ++o) stageB(o, 0, 0);
#pragma unroll
  for (int o = 0; o < 4; ++o) stageA(o, 1, 1);
#pragma unroll
  for (int o = 0; o < 4; ++o) stageB(o, 1, 1);
  asm volatile("s_waitcnt vmcnt(8)" ::: "memory");  // tile 0 landed; tile 1 in flight
  __builtin_amdgcn_s_barrier();

  f16x8 aF[4][2], bF[4][2];

  for (int kt = 0; kt < KB; ++kt) {
    const int s = kt & 1;
    const bool st1 = (kt + 1 < KB);
    const bool st2 = (kt + 2 < KB);

    // ---- phase 0: read all B + A-half0 fragments; MFMA (h0, fn0-1) ----
#pragma unroll
    for (int f = 0; f < 4; ++f)
#pragma unroll
      for (int ks = 0; ks < 2; ++ks) aF[f][ks] = lda(s, 0, f, ks);
#pragma unroll
    for (int q = 0; q < 4; ++q)
#pragma unroll
      for (int ks = 0; ks < 2; ++ks) bF[q][ks] = ldb(s, q, ks);
    __builtin_amdgcn_s_barrier();
    __builtin_amdgcn_s_setprio(1);
#pragma unroll
    for (int f = 0; f < 4; ++f)
#pragma unroll
      for (int fn = 0; fn < 2; ++fn)
#pragma unroll
        for (int ks = 0; ks < 2; ++ks)
          acc[f][fn] = __builtin_amdgcn_mfma_f32_16x16x32_f16(aF[f][ks], bF[fn][ks], acc[f][fn], 0, 0, 0);
    __builtin_amdgcn_s_setprio(0);
    __builtin_amdgcn_s_barrier();

    // ---- phase 1: stage B(kt+2) -> B[s]; MFMA (h0, fn2-3) ----
    if (st2) {
#pragma unroll
      for (int o = 0; o < 4; ++o) stageB(o, kt + 2, s);
    }
    __builtin_amdgcn_s_barrier();
    __builtin_amdgcn_s_setprio(1);
#pragma unroll
    for (int f = 0; f < 4; ++f)
#pragma unroll
      for (int fn = 2; fn < 4; ++fn)
#pragma unroll
        for (int ks = 0; ks < 2; ++ks)
          acc[f][fn] = __builtin_amdgcn_mfma_f32_16x16x32_f16(aF[f][ks], bF[fn][ks], acc[f][fn], 0, 0, 0);
    __builtin_amdgcn_s_setprio(0);
    __builtin_amdgcn_s_barrier();

    // ---- phase 2: read A-half1; stage A(kt+2) ops 0,2; MFMA (h1, fn0-1) ----
#pragma unroll
    for (int f = 0; f < 4; ++f)
#pragma unroll
      for (int ks = 0; ks < 2; ++ks) aF[f][ks] = lda(s, 1, f, ks);
    if (st2) { stageA(0, kt + 2, s); stageA(2, kt + 2, s); }
    __builtin_amdgcn_s_barrier();
    __builtin_amdgcn_s_setprio(1);
#pragma unroll
    for (int f = 0; f < 4; ++f)
#pragma unroll
      for (int fn = 0; fn < 2; ++fn)
#pragma unroll
        for (int ks = 0; ks < 2; ++ks)
          acc[4 + f][fn] = __builtin_amdgcn_mfma_f32_16x16x32_f16(aF[f][ks], bF[fn][ks], acc[4 + f][fn], 0, 0, 0);
    __builtin_amdgcn_s_setprio(0);
    __builtin_amdgcn_s_barrier();

    // ---- phase 3: stage A(kt+2) ops 1,3; MFMA (h1, fn2-3); counted wait ----
    if (st2) { stageA(1, kt + 2, s); stageA(3, kt + 2, s); }
    __builtin_amdgcn_s_setprio(1);
#pragma unroll
    for (int f = 0; f < 4; ++f)
#pragma unroll
      for (int fn = 2; fn < 4; ++fn)
#pragma unroll
        for (int ks = 0; ks < 2; ++ks)
          acc[4 + f][fn] = __builtin_amdgcn_mfma_f32_16x16x32_f16(aF[f][ks], bF[fn][ks], acc[4 + f][fn], 0, 0, 0);
    __builtin_amdgcn_s_setprio(0);
    if (st2) {
      asm volatile("s_waitcnt vmcnt(8)" ::: "memory");
    } else if (st1) {
      asm volatile("s_waitcnt vmcnt(0)" ::: "memory");
    }
    __builtin_amdgcn_s_barrier();
  }

  // ---- fused LSTM epilogue ----
  float bq[4];
#pragma unroll
  for (int q = 0; q < 4; ++q) bq[q] = biasp[n0 + wc * 64 + q * 16 + lr];
  const int j = ((n0 + wc * 64) >> 6) * 16 + lr;
  const size_t segoff = (size_t)T * BATCH * HDIM + (size_t)2 * BATCH * HDIM;

#pragma unroll
  for (int fm = 0; fm < 8; ++fm) {
#pragma unroll
    for (int reg = 0; reg < 4; ++reg) {
      int m = m0 + wr * 128 + fm * 16 + ((lane >> 4) << 2) + reg;
      if (m >= mk) continue;
      int4 mt = metaS[m - m0];
      float gi = acc[fm][0][reg] + bq[0];
      float gf = acc[fm][1][reg] + bq[1];
      float gg = acc[fm][2][reg] + bq[2];
      float go = acc[fm][3][reg] + bq[3];
      float iv = sigmoidf_(gi), fv = sigmoidf_(gf);
      float gv = tanhf_(gg), ov = sigmoidf_(go);
      float cp, hp;
      if (FIRST) { cp = 0.f; hp = 0.f; }
      else {
        cp = cst[(size_t)m * HDIM + j];
        hp = (float)hprev[(size_t)m * HDIM + j];
      }
      float cn = fv * cp + iv * gv;
      float hn = ov * tanhf_(cn);
      float hz = ZK * hp + (1.f - ZK) * hn;
      float cz = ZK * cp + (1.f - ZK) * cn;
      out[((size_t)(mt.x + k) * BATCH + mt.y) * HDIM + j] = hz;
      if (k == mt.w - 1) {
        out[segoff + ((size_t)mt.y * SEGS + mt.z) * HDIM + j] = hz;
      } else {
        hnext[(size_t)m * HDIM + j] = (f16)hz;
        cst[(size_t)m * HDIM + j] = cz;
      }
    }
  }
}

// ============ TAIL: 128x128 4-wave kernel, row-affinity XCD swizzle ============
template <bool FIRST>
__global__ void step_kernel(const f16* __restrict__ xh, const f16* __restrict__ Wc,
                            const float* __restrict__ biasp,
                            const f16* __restrict__ hprev, f16* __restrict__ hnext,
                            float* __restrict__ cst,
                            const int4* __restrict__ meta, const int* __restrict__ Mk,
                            float* __restrict__ out, int T, int k) {
  const int mk = Mk[k];
  // grid (16,64): id 0..1023; xcd = id&7; by%8 == xcd (interleaved row affinity)
  const int id = blockIdx.y * 16 + blockIdx.x;
  const int xcd = id & 7, slot = id >> 3;   // slot 0..127
  const int by = (slot & 7) * 8 + xcd;      // row-block 0..63
  const int bx = slot >> 3;                 // col-block 0..15
  const int m0 = by * 128;
  if (m0 >= mk) return;
  const int n0 = bx * 128;

  __shared__ __align__(16) f16 At[128][64];
  __shared__ __align__(16) f16 Bt[128][64];
  __shared__ int4 metaS[128];

  const int tid = threadIdx.x;
  const int lane = tid & 63;
  const int w = tid >> 6;
  const int wr = w >> 1, wc = w & 1;

  if (tid < 128) metaS[tid] = meta[m0 + tid];

  const f16* xsrc[4];
  const f16* hsrc[4];
  const f16* wsrc[4];
#pragma unroll
  for (int i = 0; i < 4; ++i) {
    int r = m0 + w * 32 + i * 8 + (lane >> 3);
    int ra = (r < mk) ? r : 0;
    int4 mt = meta[ra];
    xsrc[i] = xh + ((size_t)(mt.x + k) * BATCH + mt.y) * IDIM;
    hsrc[i] = hprev + (size_t)ra * HDIM;
    wsrc[i] = Wc + (size_t)(n0 + w * 32 + i * 8 + (lane >> 3)) * 1024;
  }
  const int koff = (lane & 7) * 8;

  f32x4 acc[4][4];
#pragma unroll
  for (int a = 0; a < 4; ++a)
#pragma unroll
    for (int bb = 0; bb < 4; ++bb) acc[a][bb] = (f32x4){0.f, 0.f, 0.f, 0.f};

  const int KB = FIRST ? 8 : 16;
  for (int kb = 0; kb < KB; ++kb) {
    __syncthreads();
#pragma unroll
    for (int i = 0; i < 4; ++i) {
      const f16* s;
      if (FIRST) s = xsrc[i] + kb * 64 + koff;
      else       s = (kb < 8) ? (xsrc[i] + kb * 64 + koff) : (hsrc[i] + (kb - 8) * 64 + koff);
      gload16(s, &At[w * 32 + i * 8][0]);
    }
#pragma unroll
    for (int i = 0; i < 4; ++i) gload16(wsrc[i] + kb * 64 + koff, &Bt[w * 32 + i * 8][0]);
    __syncthreads();

    const int lr = lane & 15;
    const int lk = (lane >> 4) * 8;
#pragma unroll
    for (int ks = 0; ks < 2; ++ks) {
      f16x8 af[4], bfr[4];
#pragma unroll
      for (int f = 0; f < 4; ++f) af[f] = *(const f16x8*)&At[wr * 64 + f * 16 + lr][ks * 32 + lk];
#pragma unroll
      for (int f = 0; f < 4; ++f) bfr[f] = *(const f16x8*)&Bt[wc * 64 + f * 16 + lr][ks * 32 + lk];
#pragma unroll
      for (int fm = 0; fm < 4; ++fm)
#pragma unroll
        for (int fn = 0; fn < 4; ++fn)
          acc[fm][fn] = __builtin_amdgcn_mfma_f32_16x16x32_f16(af[fm], bfr[fn], acc[fm][fn], 0, 0, 0);
    }
  }

  const int r15 = lane & 15;
  float bq[4];
#pragma unroll
  for (int q = 0; q < 4; ++q) bq[q] = biasp[n0 + wc * 64 + q * 16 + r15];
  const int j = ((n0 + wc * 64) >> 6) * 16 + r15;
  const size_t segoff = (size_t)T * BATCH * HDIM + (size_t)2 * BATCH * HDIM;

#pragma unroll
  for (int fm = 0; fm < 4; ++fm) {
#pragma unroll
    for (int reg = 0; reg < 4; ++reg) {
      int m = m0 + wr * 64 + fm * 16 + ((lane >> 4) << 2) + reg;
      if (m >= mk) continue;
      int4 mt = metaS[m - m0];
      float gi = acc[fm][0][reg] + bq[0];
      float gf = acc[fm][1][reg] + bq[1];
      float gg = acc[fm][2][reg] + bq[2];
      float go = acc[fm][3][reg] + bq[3];
      float iv = sigmoidf_(gi), fv = sigmoidf_(gf);
      float gv = tanhf_(gg), ov = sigmoidf_(go);
      float cp, hp;
      if (FIRST) { cp = 0.f; hp = 0.f; }
      else {
        cp = cst[(size_t)m * HDIM + j];
        hp = (float)hprev[(size_t)m * HDIM + j];
      }
      float cn = fv * cp + iv * gv;
      float hn = ov * tanhf_(cn);
      float hz = ZK * hp + (1.f - ZK) * hn;
      float cz = ZK * cp + (1.f - ZK) * cn;
      out[((size_t)(mt.x + k) * BATCH + mt.y) * HDIM + j] = hz;
      if (k == mt.w - 1) {
        out[segoff + ((size_t)mt.y * SEGS + mt.z) * HDIM + j] = hz;
      } else {
        hnext[(size_t)m * HDIM + j] = (f16)hz;
        cst[(size_t)m * HDIM + j] = cz;
      }
    }
  }
}

extern "C" void kernel_launch(void* const* d_in, const int* in_sizes, int n_in,
                              void* d_out, int out_size, void* d_ws, size_t ws_size,
                              hipStream_t stream) {
  const float* x = (const float*)d_in[0];
  const int* durs = (const int*)d_in[1];
  const float* Wih = (const float*)d_in[2];
  const float* Whh = (const float*)d_in[3];
  const float* bih = (const float*)d_in[4];
  const float* bhh = (const float*)d_in[5];
  float* out = (float*)d_out;
  const int T = in_sizes[0] / (BATCH * IDIM);

  char* ws = (char*)d_ws;
  size_t off = 0;
  auto alloc = [&](size_t bytes) {
    void* p = ws + off;
    off = (off + bytes + 255) & ~(size_t)255;
    return p;
  };
  f16* xh     = (f16*)alloc((size_t)T * BATCH * IDIM * 2);
  f16* Wc     = (f16*)alloc((size_t)NGATE * 1024 * 2);
  float* biasp= (float*)alloc((size_t)NGATE * 4);
  f16* hst0   = (f16*)alloc((size_t)SEGS * BATCH * HDIM * 2);
  f16* hst1   = (f16*)alloc((size_t)SEGS * BATCH * HDIM * 2);
  float* cst  = (float*)alloc((size_t)SEGS * BATCH * HDIM * 4);
  int4* meta  = (int4*)alloc((size_t)SEGS * BATCH * 16);
  int* Mk     = (int*)alloc(64);
  int* mel    = (int*)alloc(64);

  prep_kernel<<<1, 64, 0, stream>>>(durs, meta, Mk, mel);
  wprep_kernel<<<NGATE, 256, 0, stream>>>(Wih, Whh, bih, bhh, Wc, biasp);
  long n8 = (long)T * BATCH * IDIM / 8;
  xconv_kernel<<<2048, 256, 0, stream>>>(x, xh, n8);
  zero_kernel<<<2048, 128, 0, stream>>>(out, mel, T, T * BATCH + 128);

  // head: k=0..7 on the 256^2 8-wave counted-vmcnt kernel (row-affinity XCD swizzle)
  dim3 hgrid(8, 32);  // x: N/256, y: M/256
  step256_kernel<true><<<hgrid, 512, 0, stream>>>(xh, Wc, biasp, hst0, hst1, cst, meta, Mk, out, T, 0);
  for (int k = 1; k < 8; ++k) {
    f16* hp = (k & 1) ? hst1 : hst0;
    f16* hn = (k & 1) ? hst0 : hst1;
    step256_kernel<false><<<hgrid, 512, 0, stream>>>(xh, Wc, biasp, hp, hn, cst, meta, Mk, out, T, k);
  }
  // tail: k=8..11 on the 128^2 kernel (row-affinity XCD swizzle)
  dim3 sgrid(16, 64);  // x: N/128, y: M/128
  for (int k = 8; k < 12; ++k) {
    f16* hp = (k & 1) ? hst1 : hst0;
    f16* hn = (k & 1) ? hst0 : hst1;
    step_kernel<false><<<sgrid, 256, 0, stream>>>(xh, Wc, biasp, hp, hn, cst, meta, Mk, out, T, k);
  }
}

// Round 7
// 693.940 us; speedup vs baseline: 1.1858x; 1.0457x over previous
//
#include <hip/hip_runtime.h>
#include <hip/hip_fp16.h>

#define IDIM 512
#define HDIM 512
#define NGATE 2048
#define SEGS 128
#define BATCH 64
#define ZK 0.1f

typedef _Float16 f16;
typedef _Float16 f16x8 __attribute__((ext_vector_type(8)));
typedef float f32x4 __attribute__((ext_vector_type(4)));

__device__ __forceinline__ void gload16(const void* g, void* l) {
  __builtin_amdgcn_global_load_lds((const __attribute__((address_space(1))) void*)g,
                                   (__attribute__((address_space(3))) void*)l, 16, 0, 0);
}
__device__ __forceinline__ float sigmoidf_(float x) { return 1.0f / (1.0f + __expf(-x)); }
__device__ __forceinline__ float tanhf_(float x) { return 2.0f / (1.0f + __expf(-2.0f * x)) - 1.0f; }

// ---------------- prep: starts, counting-sort by dur desc, Mk, mel_len ----------------
__global__ void prep_kernel(const int* __restrict__ durs, int4* __restrict__ meta,
                            int* __restrict__ Mk, int* __restrict__ mel) {
  __shared__ int hist[16];
  __shared__ int cur[16];
  int tid = threadIdx.x;  // 64 threads, one per batch element
  if (tid < 16) hist[tid] = 0;
  __syncthreads();
  int b = tid;
  for (int s = 0; s < SEGS; ++s) atomicAdd(&hist[durs[s * BATCH + b] & 15], 1);
  __syncthreads();
  if (tid == 0) {
    int run = 0;
    for (int d = 15; d >= 0; --d) { cur[d] = run; run += hist[d]; }
    for (int kk = 0; kk < 12; ++kk) Mk[kk] = cur[kk];
  }
  __syncthreads();
  int run = 0;
  for (int s = 0; s < SEGS; ++s) {
    int d = durs[s * BATCH + b] & 15;
    int pos = atomicAdd(&cur[d], 1);
    meta[pos] = make_int4(run, b, s, d);  // start, b, s, dur
    run += d;
  }
  mel[b] = run;
}

// ---------------- W prep: permuted combined weight (fp16) + bias ----------------
__global__ void wprep_kernel(const float* __restrict__ Wih, const float* __restrict__ Whh,
                             const float* __restrict__ bih, const float* __restrict__ bhh,
                             f16* __restrict__ Wc, float* __restrict__ biasp) {
  int n = blockIdx.x;
  int G = n >> 6, q = (n >> 4) & 3, r = n & 15;
  int j = G * 16 + r;
  int orig = q * 512 + j;
  for (int kk = threadIdx.x; kk < 1024; kk += blockDim.x) {
    float v = (kk < 512) ? Wih[(size_t)orig * 512 + kk] : Whh[(size_t)orig * 512 + kk - 512];
    Wc[(size_t)n * 1024 + kk] = (f16)v;
  }
  if (threadIdx.x == 0) biasp[n] = bih[orig] + bhh[orig];
}

// ---------------- x: fp32 -> fp16 ----------------
__global__ void xconv_kernel(const float* __restrict__ x, f16* __restrict__ xh, long n8) {
  long i = (long)blockIdx.x * blockDim.x + threadIdx.x;
  long stride = (long)gridDim.x * blockDim.x;
  for (; i < n8; i += stride) {
    const float4* p = (const float4*)(x + i * 8);
    float4 a = p[0], bv = p[1];
    f16x8 o;
    o[0] = (f16)a.x;  o[1] = (f16)a.y;  o[2] = (f16)a.z;  o[3] = (f16)a.w;
    o[4] = (f16)bv.x; o[5] = (f16)bv.y; o[6] = (f16)bv.z; o[7] = (f16)bv.w;
    *(f16x8*)(xh + i * 8) = o;
  }
}

// ---------------- zero invalid output rows + h + c (grid-stride) ----------------
__global__ void zero_kernel(float* __restrict__ out, const int* __restrict__ mel,
                            int T, int total) {
  int tb = T * BATCH;
  for (int bid = blockIdx.x; bid < total; bid += gridDim.x) {
    if (bid < tb) {
      int t = bid / BATCH, b = bid - t * BATCH;
      if (t < mel[b]) continue;
      float4* p = (float4*)(out + (size_t)bid * HDIM);
      p[threadIdx.x] = make_float4(0.f, 0.f, 0.f, 0.f);
    } else {
      int e = bid - tb;
      float4* p = (float4*)(out + (size_t)tb * HDIM + (size_t)e * HDIM);
      p[threadIdx.x] = make_float4(0.f, 0.f, 0.f, 0.f);
    }
  }
}

// ============ HEAD: 256x256xBK64 fused (K=1024), 4 waves x (128x128 tile) ============
// Big wave-tile: A-frags reused over 8 n-frags -> LDS reads 128 b128/K-tile/CU (was 192).
// 2 phases/K-tile, depth-2 prefetch with counted vmcnt(16).
template <bool FIRST>
__global__ __launch_bounds__(256, 1)
void step256_kernel(const f16* __restrict__ xh, const f16* __restrict__ Wc,
                    const float* __restrict__ biasp,
                    const f16* __restrict__ hprev, f16* __restrict__ hnext,
                    float* __restrict__ cst,
                    const int4* __restrict__ meta, const int* __restrict__ Mk,
                    float* __restrict__ out, int T, int k) {
  const int mk = Mk[k];
  // bijective chunked XCD swizzle (round-3 form; nwg=256, %8==0)
  const int id = blockIdx.y * 8 + blockIdx.x;
  const int swz = (id & 7) * 32 + (id >> 3);
  const int by = swz >> 3, bx = swz & 7;
  const int m0 = by * 256;
  if (m0 >= mk) return;
  const int n0 = bx * 256;

  __shared__ __align__(16) f16 As[2][256][64];
  __shared__ __align__(16) f16 Bs[2][256][64];
  __shared__ int4 metaS[256];

  const int tid = threadIdx.x;
  const int lane = tid & 63;
  const int w = tid >> 6;          // 0..3
  const int wr = w >> 1;           // 0..1 : rows wr*128..+128
  const int wc = w & 1;            // 0..1 : cols wc*128..+128
  const int lr = lane & 15;
  const int lk = lane >> 4;        // 0..3

  metaS[tid] = meta[m0 + tid];     // 256 threads cover 256 rows

  // --- staging setup: 8 A-instrs + 8 B-instrs per wave per K-tile ---
  const int swzc = (((lane & 7) ^ ((lane >> 3) & 7)) << 3);  // source chunk pre-swizzle
  unsigned xoff[8];
  int ra8[8];
#pragma unroll
  for (int o = 0; o < 8; ++o) {
    int trow = o * 32 + w * 8 + (lane >> 3);
    int r = m0 + trow;
    int ra = (r < mk) ? r : 0;  // dead rows stage row 0 (masked in epilogue)
    int4 mt = meta[ra];
    xoff[o] = (unsigned)(((mt.x + k) * BATCH + mt.y) * IDIM + swzc);
    ra8[o] = ra;
  }

  auto stageA = [&](int o, int kb, int slot) {
    const f16* src;
    if (FIRST || kb < 8) src = xh + (size_t)xoff[o] + kb * 64;
    else src = hprev + (size_t)ra8[o] * HDIM + (kb - 8) * 64 + swzc;
    gload16(src, &As[slot][o * 32 + w * 8][0]);
  };
  auto stageB = [&](int o, int kb, int slot) {
    int trow = o * 32 + w * 8 + (lane >> 3);
    gload16(Wc + (size_t)(n0 + trow) * 1024 + (size_t)kb * 64 + swzc,
            &Bs[slot][o * 32 + w * 8][0]);
  };

  // --- swizzled fragment reads ---
  auto lda = [&](int slot, int mf, int ks) -> f16x8 {
    int row = wr * 128 + mf * 16 + lr;
    int ch = (((ks * 4 + lk) ^ (lr & 7)) << 3);
    return *(const f16x8*)&As[slot][row][ch];
  };
  auto ldb = [&](int slot, int nf, int ks) -> f16x8 {
    int row = wc * 128 + nf * 16 + lr;
    int ch = (((ks * 4 + lk) ^ (lr & 7)) << 3);
    return *(const f16x8*)&Bs[slot][row][ch];
  };

  f32x4 acc[8][8];
#pragma unroll
  for (int a = 0; a < 8; ++a)
#pragma unroll
    for (int bb = 0; bb < 8; ++bb) acc[a][bb] = (f32x4){0.f, 0.f, 0.f, 0.f};

  const int KB = FIRST ? 8 : 16;

  // prologue: prime tiles 0 (slot 0) and 1 (slot 1); counted wait
#pragma unroll
  for (int o = 0; o < 8; ++o) { stageA(o, 0, 0); }
#pragma unroll
  for (int o = 0; o < 8; ++o) { stageB(o, 0, 0); }
#pragma unroll
  for (int o = 0; o < 8; ++o) { stageA(o, 1, 1); }
#pragma unroll
  for (int o = 0; o < 8; ++o) { stageB(o, 1, 1); }
  asm volatile("s_waitcnt vmcnt(16)" ::: "memory");  // tile 0 landed; tile 1 in flight
  __builtin_amdgcn_s_barrier();

  for (int kt = 0; kt < KB; ++kt) {
    const int s = kt & 1;
    const bool st1 = (kt + 1 < KB);
    const bool st2 = (kt + 2 < KB);

    f16x8 bF[8][2], aF0[8], aF1[8];
    // all reads of slot s up front (B both halves, A half 0)
#pragma unroll
    for (int nf = 0; nf < 8; ++nf) {
      bF[nf][0] = ldb(s, nf, 0);
      bF[nf][1] = ldb(s, nf, 1);
    }
#pragma unroll
    for (int mf = 0; mf < 8; ++mf) aF0[mf] = lda(s, mf, 0);

    // MFMA ks=0 (64) — overlaps the aF1 reads below via ILP
    __builtin_amdgcn_s_setprio(1);
#pragma unroll
    for (int mf = 0; mf < 8; ++mf)
#pragma unroll
      for (int nf = 0; nf < 8; ++nf)
        acc[mf][nf] = __builtin_amdgcn_mfma_f32_16x16x32_f16(aF0[mf], bF[nf][0], acc[mf][nf], 0, 0, 0);
    __builtin_amdgcn_s_setprio(0);

#pragma unroll
    for (int mf = 0; mf < 8; ++mf) aF1[mf] = lda(s, mf, 1);

    __builtin_amdgcn_s_barrier();  // all waves done reading slot s

    // stage tile kt+2 into slot s (safe post-barrier), overlapped with MFMA ks=1
    if (st2) {
#pragma unroll
      for (int o = 0; o < 8; ++o) { stageA(o, kt + 2, s); }
#pragma unroll
      for (int o = 0; o < 8; ++o) { stageB(o, kt + 2, s); }
    }

    __builtin_amdgcn_s_setprio(1);
#pragma unroll
    for (int mf = 0; mf < 8; ++mf)
#pragma unroll
      for (int nf = 0; nf < 8; ++nf)
        acc[mf][nf] = __builtin_amdgcn_mfma_f32_16x16x32_f16(aF1[mf], bF[nf][1], acc[mf][nf], 0, 0, 0);
    __builtin_amdgcn_s_setprio(0);

    // tile boundary: ensure kt+1 landed, keep kt+2's 16 loads in flight
    if (st2) {
      asm volatile("s_waitcnt vmcnt(16)" ::: "memory");
    } else if (st1) {
      asm volatile("s_waitcnt vmcnt(0)" ::: "memory");
    }
    __builtin_amdgcn_s_barrier();
  }

  // ---- fused LSTM epilogue: wave covers 2 gate-groups (g2) of 64 cols each ----
  float bq[2][4];
#pragma unroll
  for (int g2 = 0; g2 < 2; ++g2)
#pragma unroll
    for (int q = 0; q < 4; ++q)
      bq[g2][q] = biasp[n0 + wc * 128 + g2 * 64 + q * 16 + lr];
  int jg[2];
#pragma unroll
  for (int g2 = 0; g2 < 2; ++g2)
    jg[g2] = ((n0 + wc * 128 + g2 * 64) >> 6) * 16 + lr;
  const size_t segoff = (size_t)T * BATCH * HDIM + (size_t)2 * BATCH * HDIM;

#pragma unroll
  for (int mf = 0; mf < 8; ++mf) {
#pragma unroll
    for (int reg = 0; reg < 4; ++reg) {
      int m = m0 + wr * 128 + mf * 16 + ((lane >> 4) << 2) + reg;
      if (m >= mk) continue;
      int4 mt = metaS[m - m0];
#pragma unroll
      for (int g2 = 0; g2 < 2; ++g2) {
        int j = jg[g2];
        float gi = acc[mf][g2 * 4 + 0][reg] + bq[g2][0];
        float gf = acc[mf][g2 * 4 + 1][reg] + bq[g2][1];
        float gg = acc[mf][g2 * 4 + 2][reg] + bq[g2][2];
        float go = acc[mf][g2 * 4 + 3][reg] + bq[g2][3];
        float iv = sigmoidf_(gi), fv = sigmoidf_(gf);
        float gv = tanhf_(gg), ov = sigmoidf_(go);
        float cp, hp;
        if (FIRST) { cp = 0.f; hp = 0.f; }
        else {
          cp = cst[(size_t)m * HDIM + j];
          hp = (float)hprev[(size_t)m * HDIM + j];
        }
        float cn = fv * cp + iv * gv;
        float hn = ov * tanhf_(cn);
        float hz = ZK * hp + (1.f - ZK) * hn;
        float cz = ZK * cp + (1.f - ZK) * cn;
        out[((size_t)(mt.x + k) * BATCH + mt.y) * HDIM + j] = hz;
        if (k == mt.w - 1) {
          out[segoff + ((size_t)mt.y * SEGS + mt.z) * HDIM + j] = hz;
        } else {
          hnext[(size_t)m * HDIM + j] = (f16)hz;
          cst[(size_t)m * HDIM + j] = cz;
        }
      }
    }
  }
}

// ============ TAIL: 128x128 4-wave kernel (round-3 exact form) ============
template <bool FIRST>
__global__ void step_kernel(const f16* __restrict__ xh, const f16* __restrict__ Wc,
                            const float* __restrict__ biasp,
                            const f16* __restrict__ hprev, f16* __restrict__ hnext,
                            float* __restrict__ cst,
                            const int4* __restrict__ meta, const int* __restrict__ Mk,
                            float* __restrict__ out, int T, int k) {
  const int mk = Mk[k];
  const int m0 = blockIdx.y * 128;
  if (m0 >= mk) return;
  const int n0 = blockIdx.x * 128;

  __shared__ __align__(16) f16 At[128][64];
  __shared__ __align__(16) f16 Bt[128][64];
  __shared__ int4 metaS[128];

  const int tid = threadIdx.x;
  const int lane = tid & 63;
  const int w = tid >> 6;
  const int wr = w >> 1, wc = w & 1;

  if (tid < 128) metaS[tid] = meta[m0 + tid];

  const f16* xsrc[4];
  const f16* hsrc[4];
  const f16* wsrc[4];
#pragma unroll
  for (int i = 0; i < 4; ++i) {
    int r = m0 + w * 32 + i * 8 + (lane >> 3);
    int ra = (r < mk) ? r : 0;
    int4 mt = meta[ra];
    xsrc[i] = xh + ((size_t)(mt.x + k) * BATCH + mt.y) * IDIM;
    hsrc[i] = hprev + (size_t)ra * HDIM;
    wsrc[i] = Wc + (size_t)(n0 + w * 32 + i * 8 + (lane >> 3)) * 1024;
  }
  const int koff = (lane & 7) * 8;

  f32x4 acc[4][4];
#pragma unroll
  for (int a = 0; a < 4; ++a)
#pragma unroll
    for (int bb = 0; bb < 4; ++bb) acc[a][bb] = (f32x4){0.f, 0.f, 0.f, 0.f};

  const int KB = FIRST ? 8 : 16;
  for (int kb = 0; kb < KB; ++kb) {
    __syncthreads();
#pragma unroll
    for (int i = 0; i < 4; ++i) {
      const f16* s;
      if (FIRST) s = xsrc[i] + kb * 64 + koff;
      else       s = (kb < 8) ? (xsrc[i] + kb * 64 + koff) : (hsrc[i] + (kb - 8) * 64 + koff);
      gload16(s, &At[w * 32 + i * 8][0]);
    }
#pragma unroll
    for (int i = 0; i < 4; ++i) gload16(wsrc[i] + kb * 64 + koff, &Bt[w * 32 + i * 8][0]);
    __syncthreads();

    const int lr = lane & 15;
    const int lk = (lane >> 4) * 8;
#pragma unroll
    for (int ks = 0; ks < 2; ++ks) {
      f16x8 af[4], bfr[4];
#pragma unroll
      for (int f = 0; f < 4; ++f) af[f] = *(const f16x8*)&At[wr * 64 + f * 16 + lr][ks * 32 + lk];
#pragma unroll
      for (int f = 0; f < 4; ++f) bfr[f] = *(const f16x8*)&Bt[wc * 64 + f * 16 + lr][ks * 32 + lk];
#pragma unroll
      for (int fm = 0; fm < 4; ++fm)
#pragma unroll
        for (int fn = 0; fn < 4; ++fn)
          acc[fm][fn] = __builtin_amdgcn_mfma_f32_16x16x32_f16(af[fm], bfr[fn], acc[fm][fn], 0, 0, 0);
    }
  }

  const int r15 = lane & 15;
  float bq[4];
#pragma unroll
  for (int q = 0; q < 4; ++q) bq[q] = biasp[n0 + wc * 64 + q * 16 + r15];
  const int j = ((n0 + wc * 64) >> 6) * 16 + r15;
  const size_t segoff = (size_t)T * BATCH * HDIM + (size_t)2 * BATCH * HDIM;

#pragma unroll
  for (int fm = 0; fm < 4; ++fm) {
#pragma unroll
    for (int reg = 0; reg < 4; ++reg) {
      int m = m0 + wr * 64 + fm * 16 + ((lane >> 4) << 2) + reg;
      if (m >= mk) continue;
      int4 mt = metaS[m - m0];
      float gi = acc[fm][0][reg] + bq[0];
      float gf = acc[fm][1][reg] + bq[1];
      float gg = acc[fm][2][reg] + bq[2];
      float go = acc[fm][3][reg] + bq[3];
      float iv = sigmoidf_(gi), fv = sigmoidf_(gf);
      float gv = tanhf_(gg), ov = sigmoidf_(go);
      float cp, hp;
      if (FIRST) { cp = 0.f; hp = 0.f; }
      else {
        cp = cst[(size_t)m * HDIM + j];
        hp = (float)hprev[(size_t)m * HDIM + j];
      }
      float cn = fv * cp + iv * gv;
      float hn = ov * tanhf_(cn);
      float hz = ZK * hp + (1.f - ZK) * hn;
      float cz = ZK * cp + (1.f - ZK) * cn;
      out[((size_t)(mt.x + k) * BATCH + mt.y) * HDIM + j] = hz;
      if (k == mt.w - 1) {
        out[segoff + ((size_t)mt.y * SEGS + mt.z) * HDIM + j] = hz;
      } else {
        hnext[(size_t)m * HDIM + j] = (f16)hz;
        cst[(size_t)m * HDIM + j] = cz;
      }
    }
  }
}

extern "C" void kernel_launch(void* const* d_in, const int* in_sizes, int n_in,
                              void* d_out, int out_size, void* d_ws, size_t ws_size,
                              hipStream_t stream) {
  const float* x = (const float*)d_in[0];
  const int* durs = (const int*)d_in[1];
  const float* Wih = (const float*)d_in[2];
  const float* Whh = (const float*)d_in[3];
  const float* bih = (const float*)d_in[4];
  const float* bhh = (const float*)d_in[5];
  float* out = (float*)d_out;
  const int T = in_sizes[0] / (BATCH * IDIM);

  char* ws = (char*)d_ws;
  size_t off = 0;
  auto alloc = [&](size_t bytes) {
    void* p = ws + off;
    off = (off + bytes + 255) & ~(size_t)255;
    return p;
  };
  f16* xh     = (f16*)alloc((size_t)T * BATCH * IDIM * 2);
  f16* Wc     = (f16*)alloc((size_t)NGATE * 1024 * 2);
  float* biasp= (float*)alloc((size_t)NGATE * 4);
  f16* hst0   = (f16*)alloc((size_t)SEGS * BATCH * HDIM * 2);
  f16* hst1   = (f16*)alloc((size_t)SEGS * BATCH * HDIM * 2);
  float* cst  = (float*)alloc((size_t)SEGS * BATCH * HDIM * 4);
  int4* meta  = (int4*)alloc((size_t)SEGS * BATCH * 16);
  int* Mk     = (int*)alloc(64);
  int* mel    = (int*)alloc(64);

  prep_kernel<<<1, 64, 0, stream>>>(durs, meta, Mk, mel);
  wprep_kernel<<<NGATE, 256, 0, stream>>>(Wih, Whh, bih, bhh, Wc, biasp);
  long n8 = (long)T * BATCH * IDIM / 8;
  xconv_kernel<<<2048, 256, 0, stream>>>(x, xh, n8);
  zero_kernel<<<2048, 128, 0, stream>>>(out, mel, T, T * BATCH + 128);

  // head: k=0..7 on the 256^2 4-wave big-tile kernel
  dim3 hgrid(8, 32);  // x: N/256, y: M/256
  step256_kernel<true><<<hgrid, 256, 0, stream>>>(xh, Wc, biasp, hst0, hst1, cst, meta, Mk, out, T, 0);
  for (int k = 1; k < 8; ++k) {
    f16* hp = (k & 1) ? hst1 : hst0;
    f16* hn = (k & 1) ? hst0 : hst1;
    step256_kernel<false><<<hgrid, 256, 0, stream>>>(xh, Wc, biasp, hp, hn, cst, meta, Mk, out, T, k);
  }
  // tail: k=8..11 on the 128^2 kernel
  dim3 sgrid(16, 64);  // x: N/128, y: M/128
  for (int k = 8; k < 12; ++k) {
    f16* hp = (k & 1) ? hst1 : hst0;
    f16* hn = (k & 1) ? hst0 : hst1;
    step_kernel<false><<<sgrid, 256, 0, stream>>>(xh, Wc, biasp, hp, hn, cst, meta, Mk, out, T, k);
  }
}